// Round 1
// baseline (1013.225 us; speedup 1.0000x reference)
//
#include <hip/hip_runtime.h>

// MaxPoolFaceFeature: out[m,c,f] = max(fea[m,c,f], max_k fea[m,c,ring_n[m,f,k]])
// fea:   [M=8, C=256, F=20000] float32
// ring:  [M=8, F=20000, K=3]   int32 (harness delivers integers as int32)
// out:   [M=8, C=256, F=20000] float32

#define NM 8
#define NC 256
#define NF 20000
#define NK 3
#define FT 64   // faces per block

__global__ __launch_bounds__(256) void MaxPoolFaceFeature_kernel(
    const float* __restrict__ fea,
    const int*   __restrict__ ring,
    float*       __restrict__ out)
{
    const int tid     = threadIdx.x;
    const int f_local = tid & 63;        // lane-contiguous face -> coalesced f reads/writes
    const int c0      = tid >> 6;        // channel group 0..3

    const int blocks_per_mesh = (NF + FT - 1) / FT;   // 313
    const int m      = blockIdx.x / blocks_per_mesh;
    const int f_base = (blockIdx.x % blocks_per_mesh) * FT;
    const int f      = f_base + f_local;
    if (f >= NF) return;

    const long mo = (long)m * NC * NF;
    const float* feam = fea + mo;
    float*       outm = out + mo;

    // Load neighbor indices once per face; reused for all 64 channels this
    // thread handles (256x amortization vs per-element re-read).
    const int* r = ring + ((long)m * NF + f) * NK;
    const int r0 = r[0];
    const int r1 = r[1];
    const int r2 = r[2];

    #pragma unroll 4
    for (int c = c0; c < NC; c += 4) {
        const float* row = feam + (long)c * NF;
        float v  = row[f];    // coalesced across the 64 face-lanes
        float a  = row[r0];   // gather (L1/L2)
        float b  = row[r1];
        float d  = row[r2];
        float mx = fmaxf(fmaxf(v, a), fmaxf(b, d));
        outm[(long)c * NF + f] = mx;
    }
}

extern "C" void kernel_launch(void* const* d_in, const int* in_sizes, int n_in,
                              void* d_out, int out_size, void* d_ws, size_t ws_size,
                              hipStream_t stream) {
    const float* fea  = (const float*)d_in[0];
    const int*   ring = (const int*)d_in[1];
    float*       out  = (float*)d_out;

    const int blocks_per_mesh = (NF + FT - 1) / FT;  // 313
    const int grid = NM * blocks_per_mesh;           // 2504
    MaxPoolFaceFeature_kernel<<<grid, 256, 0, stream>>>(fea, ring, out);
}

// Round 2
// 452.538 us; speedup vs baseline: 2.2390x; 2.2390x over previous
//
#include <hip/hip_runtime.h>

// MaxPoolFaceFeature: out[m,c,f] = max(fea[m,c,f], max_k fea[m,c,ring_n[m,f,k]])
// fea:  [M=8, C=256, F=20000] f32, ring: [M=8, F=20000, K=3] i32, out same as fea.
//
// Grid layout: blockIdx = (ct outer, ft inner) x (m = blockIdx & 7).
//  - ct outermost => all ~2K resident blocks work the SAME 32-channel tile,
//    so the gather working set is small and L2-resident (one row = 80 KB,
//    32 rows/mesh = 2.5 MB < 4 MB XCD L2).
//  - m = blockIdx & 7 => consecutive blocks round-robin meshes onto XCDs,
//    giving each XCD L2 a single mesh's channel tile.

#define NM 8
#define NC 256
#define NF 20000
#define NK 3
#define FT 64      // faces per block
#define CT 32      // channels per block (tile)
#define BPM 313    // face-tiles per mesh = ceil(20000/64)

__global__ __launch_bounds__(256) void MaxPoolFaceFeature_kernel(
    const float* __restrict__ fea,
    const int*   __restrict__ ring,
    float*       __restrict__ out)
{
    const int tid     = threadIdx.x;
    const int f_local = tid & 63;     // coalesced face lane
    const int cg      = tid >> 6;     // channel sub-group 0..3

    const int m  = blockIdx.x & 7;    // mesh -> XCD affinity
    const int t  = blockIdx.x >> 3;
    const int ct = t / BPM;           // channel tile (outermost in dispatch order)
    const int ft = t % BPM;           // face tile

    const int f = ft * FT + f_local;
    if (f >= NF) return;

    const long mo = (long)m * NC * NF;
    const float* feam = fea + mo;
    float*       outm = out + mo;

    // Neighbor indices: read once, reused for CT channels.
    const int* r = ring + ((long)m * NF + f) * NK;
    const int r0 = r[0];
    const int r1 = r[1];
    const int r2 = r[2];

    const int cbase = ct * CT + cg;   // this thread: channels cbase + 4j, j=0..7

    #pragma unroll
    for (int j = 0; j < CT / 4; ++j) {
        const int c = cbase + j * 4;
        const float* row = feam + (long)c * NF;
        float v  = row[f];            // coalesced
        float a  = row[r0];           // gathers -> L2-resident rows
        float b  = row[r1];
        float d  = row[r2];
        outm[(long)c * NF + f] = fmaxf(fmaxf(v, a), fmaxf(b, d));
    }
}

extern "C" void kernel_launch(void* const* d_in, const int* in_sizes, int n_in,
                              void* d_out, int out_size, void* d_ws, size_t ws_size,
                              hipStream_t stream) {
    const float* fea  = (const float*)d_in[0];
    const int*   ring = (const int*)d_in[1];
    float*       out  = (float*)d_out;

    const int grid = NM * (NC / CT) * BPM;   // 8 * 8 * 313 = 20032
    MaxPoolFaceFeature_kernel<<<grid, 256, 0, stream>>>(fea, ring, out);
}

// Round 3
// 85.229 us; speedup vs baseline: 11.8882x; 5.3096x over previous
//
#include <hip/hip_runtime.h>

// MaxPoolFaceFeature: out[m,c,f] = max(fea[m,c,f], max_k fea[m,c,ring_n[m,f,k]])
// fea: [M=8, C=256, F=20000] f32, ring: [M=8, F=20000, K=3] i32.
//
// Strategy: one block per (m, c). Stage the full 80 KB channel row in LDS
// (coalesced float4), then do all K=3 random gathers as ds_read_b32 —
// LDS banking resolves 64 divergent lanes in ~2-4 cyc vs ~64 serialized
// L1 transactions for a divergent global gather (the round-2 bottleneck).
// 80 KB/block -> exactly 2 blocks/CU (160 KB LDS), 512 thr = 16 waves/CU.
// m = blockIdx&7 round-robins meshes onto XCDs so each mesh's 240 KB ring
// slab stays L2-resident across its 256 channel-blocks.

#define NM 8
#define NC 256
#define NF 20000
#define NK 3
#define BT 512
#define NQ (NF / 4)   // 5000 float4 per row

__global__ __launch_bounds__(BT) void mpff_kernel(
    const float* __restrict__ fea,
    const int*   __restrict__ ring,
    float*       __restrict__ out)
{
    extern __shared__ float row[];   // NF floats = 80000 B

    const int m = blockIdx.x & 7;    // mesh -> XCD affinity
    const int c = blockIdx.x >> 3;   // channel

    const long base = ((long)m * NC + c) * NF;
    const float4* src4 = (const float4*)(fea + base);
    float4*       dst4 = (float4*)(out + base);
    float4*       row4 = (float4*)row;

    // Stage the whole channel row into LDS (coalesced, 16 B/lane).
    for (int i = threadIdx.x; i < NQ; i += BT)
        row4[i] = src4[i];
    __syncthreads();

    const int* ringm = ring + (long)m * NF * NK;

    // 4 faces per thread: int4 ring loads (48 B/thread, 16B-aligned),
    // float4 own-value LDS read, 12 random LDS gathers, float4 store.
    for (int q = threadIdx.x; q < NQ; q += BT) {
        const int4* rq = (const int4*)(ringm + q * 12);
        const int4 ra = rq[0];
        const int4 rb = rq[1];
        const int4 rc = rq[2];
        const float4 v = row4[q];
        float o0 = fmaxf(fmaxf(v.x, row[ra.x]), fmaxf(row[ra.y], row[ra.z]));
        float o1 = fmaxf(fmaxf(v.y, row[ra.w]), fmaxf(row[rb.x], row[rb.y]));
        float o2 = fmaxf(fmaxf(v.z, row[rb.z]), fmaxf(row[rb.w], row[rc.x]));
        float o3 = fmaxf(fmaxf(v.w, row[rc.y]), fmaxf(row[rc.z], row[rc.w]));
        dst4[q] = make_float4(o0, o1, o2, o3);
    }
}

extern "C" void kernel_launch(void* const* d_in, const int* in_sizes, int n_in,
                              void* d_out, int out_size, void* d_ws, size_t ws_size,
                              hipStream_t stream) {
    const float* fea  = (const float*)d_in[0];
    const int*   ring = (const int*)d_in[1];
    float*       out  = (float*)d_out;

    // 80000 B dynamic LDS > 64 KB default: raise the per-kernel cap.
    // Host-side attribute set; idempotent & graph-capture-safe (not a stream op).
    hipFuncSetAttribute((const void*)mpff_kernel,
                        hipFuncAttributeMaxDynamicSharedMemorySize, NF * 4);

    mpff_kernel<<<NM * NC, BT, NF * 4, stream>>>(fea, ring, out);
}

// Round 4
// 79.098 us; speedup vs baseline: 12.8097x; 1.0775x over previous
//
#include <hip/hip_runtime.h>

// MaxPoolFaceFeature: out[m,c,f] = max(fea[m,c,f], max_k fea[m,c,ring_n[m,f,k]])
// fea: [M=8, C=256, F=20000] f32, ring: [M=8, F=20000, K=3] i32.
//
// One block per (m, c): stage the 80 KB channel row in LDS, gather via
// ds_read_b32 (divergence-free vs serialized L1 transactions).
// R4 changes vs R3 (85 us, latency-bound, VGPR=12, 16 waves/CU):
//  - 1024 thr/block -> 2 blocks/CU (2x80 KB LDS) = 32 waves/CU.
//  - statically unrolled gather phase: NQ=5000 = 4*1024 + 904, each thread
//    runs two pair-bodies (q, q+1024) + optional tail; each body issues all
//    ring int4 loads + own-value b128 reads before the 24 LDS gathers ->
//    ~8 outstanding global ops/wave instead of 1 (R3 had VGPR=12, fully
//    serialized per-iteration chains).

#define NM 8
#define NC 256
#define NF 20000
#define NK 3
#define BT 1024
#define NQ (NF / 4)   // 5000 float4 per row

__device__ __forceinline__ float4 mp4(const float* __restrict__ row,
                                      const float4 v,
                                      const int4 ra, const int4 rb, const int4 rc)
{
    float o0 = fmaxf(fmaxf(v.x, row[ra.x]), fmaxf(row[ra.y], row[ra.z]));
    float o1 = fmaxf(fmaxf(v.y, row[ra.w]), fmaxf(row[rb.x], row[rb.y]));
    float o2 = fmaxf(fmaxf(v.z, row[rb.z]), fmaxf(row[rb.w], row[rc.x]));
    float o3 = fmaxf(fmaxf(v.w, row[rc.y]), fmaxf(row[rc.z], row[rc.w]));
    return make_float4(o0, o1, o2, o3);
}

__global__ __launch_bounds__(BT) void mpff_kernel(
    const float* __restrict__ fea,
    const int*   __restrict__ ring,
    float*       __restrict__ out)
{
    extern __shared__ float row[];   // NF floats = 80000 B

    const int m = blockIdx.x & 7;    // mesh -> XCD affinity
    const int c = blockIdx.x >> 3;   // channel

    const long base = ((long)m * NC + c) * NF;
    const float4* src4 = (const float4*)(fea + base);
    float4*       dst4 = (float4*)(out + base);
    float4*       row4 = (float4*)row;

    // Stage the whole channel row into LDS (coalesced, 16 B/lane, ~5/thread).
    for (int i = threadIdx.x; i < NQ; i += BT)
        row4[i] = src4[i];
    __syncthreads();

    const int4* ring4 = (const int4*)(ring + (long)m * NF * NK);
    const int tid = threadIdx.x;

    // ---- pair body 1: q0 = tid, q1 = tid + 1024 (both < 2048) ----
    {
        const int q0 = tid, q1 = tid + BT;
        int4 a0 = ring4[q0 * 3 + 0], b0 = ring4[q0 * 3 + 1], c0 = ring4[q0 * 3 + 2];
        int4 a1 = ring4[q1 * 3 + 0], b1 = ring4[q1 * 3 + 1], c1 = ring4[q1 * 3 + 2];
        float4 v0 = row4[q0];
        float4 v1 = row4[q1];
        dst4[q0] = mp4(row, v0, a0, b0, c0);
        dst4[q1] = mp4(row, v1, a1, b1, c1);
    }
    // ---- pair body 2: q2 = tid + 2048, q3 = tid + 3072 (both < 4096) ----
    {
        const int q0 = tid + 2 * BT, q1 = tid + 3 * BT;
        int4 a0 = ring4[q0 * 3 + 0], b0 = ring4[q0 * 3 + 1], c0 = ring4[q0 * 3 + 2];
        int4 a1 = ring4[q1 * 3 + 0], b1 = ring4[q1 * 3 + 1], c1 = ring4[q1 * 3 + 2];
        float4 v0 = row4[q0];
        float4 v1 = row4[q1];
        dst4[q0] = mp4(row, v0, a0, b0, c0);
        dst4[q1] = mp4(row, v1, a1, b1, c1);
    }
    // ---- tail: q4 = tid + 4096 (valid for tid < 904) ----
    {
        const int q4 = tid + 4 * BT;
        if (q4 < NQ) {
            int4 a = ring4[q4 * 3 + 0], b = ring4[q4 * 3 + 1], cc = ring4[q4 * 3 + 2];
            float4 v = row4[q4];
            dst4[q4] = mp4(row, v, a, b, cc);
        }
    }
}

extern "C" void kernel_launch(void* const* d_in, const int* in_sizes, int n_in,
                              void* d_out, int out_size, void* d_ws, size_t ws_size,
                              hipStream_t stream) {
    const float* fea  = (const float*)d_in[0];
    const int*   ring = (const int*)d_in[1];
    float*       out  = (float*)d_out;

    hipFuncSetAttribute((const void*)mpff_kernel,
                        hipFuncAttributeMaxDynamicSharedMemorySize, NF * 4);

    mpff_kernel<<<NM * NC, BT, NF * 4, stream>>>(fea, ring, out);
}